// Round 3
// baseline (202.355 us; speedup 1.0000x reference)
//
#include <hip/hip_runtime.h>

// Problem constants.
#define B_SZ 16384
#define C_SZ 4096
#define D_SZ 512

// Re-rank threshold in "dist units" (raw_l2/2). bf16 hi*hi dot error sigma
// ~= 0.07; max approx err ~0.4; key quantization (6 bits masked at value
// ~2^10) ~0.008. 2*0.4 + 0.02 < 1.0 = EPS.
#define EPS 1.0f
// Bias making dist' = BIAS + 0.5*csq - dot strictly positive (needs
// BIAS > 0.5*xsq; xsq ~ chi2(512) <= ~700 at 14 sigma).
#define DBIAS 1024.0f

typedef __attribute__((ext_vector_type(8))) short short8;   // 8 bf16 = 4 VGPRs
typedef __attribute__((ext_vector_type(4))) float floatx4;  // MFMA acc

// ---- helpers ---------------------------------------------------------------
__device__ inline unsigned short f2bf(float f) {
    unsigned u = __float_as_uint(f);
    unsigned r = u + 0x7FFFu + ((u >> 16) & 1u);   // round-to-nearest-even
    return (unsigned short)(r >> 16);
}
__device__ inline void gload16(const void* g, void* l) {
    // async global->LDS, 16B/lane; LDS dest = wave-uniform base + lane*16
    __builtin_amdgcn_global_load_lds(
        (const __attribute__((address_space(1))) void*)g,
        (__attribute__((address_space(3))) void*)l, 16, 0, 0);
}

// Sync primitives, R3: NO "memory" clobbers anywhere. A memory-clobbered asm
// makes the waitcnt pass treat it as a reader of all memory -> it emits
// s_waitcnt vmcnt(0) lgkmcnt(0) in front of EVERY barrier/wait, turning the
// counted pipeline into drain-per-phase (R2: 108us, MfmaUtil 27%). The raw
// builtin barrier gets no implicit drain; clobber-free asm waitcnts pinned
// with sched_barrier(0) keep the hand-counted ledger intact (rule #18).
#define BARRIER() __builtin_amdgcn_s_barrier()
#define SCHEDB()  __builtin_amdgcn_sched_barrier(0)
#define VMCNT(n)  do { SCHEDB(); asm volatile("s_waitcnt vmcnt(" #n ")"); SCHEDB(); } while (0)
#define LGKM0()   do { asm volatile("s_waitcnt lgkmcnt(0)"); SCHEDB(); } while (0)

// ---------------------------------------------------------------------------
// Prep (fused): x -> bf16 hi plane; codes -> bf16 hi plane + c_sq (fp32).
// Blocks [0, 8192): x elements. Blocks [8192, 9216): one wave per code row.
// ---------------------------------------------------------------------------
__global__ __launch_bounds__(256) void convert_kernel(const float* __restrict__ x,
                                                      const float* __restrict__ codes,
                                                      unsigned short* __restrict__ xhi,
                                                      unsigned short* __restrict__ chi,
                                                      float* __restrict__ csq) {
    const int XB = (B_SZ * D_SZ) / 4 / 256;   // 8192
    if (blockIdx.x < XB) {
        const int tid = blockIdx.x * 256 + threadIdx.x;
        const float4 v = ((const float4*)x)[tid];
        ((ushort4*)xhi)[tid] = make_ushort4(f2bf(v.x), f2bf(v.y), f2bf(v.z), f2bf(v.w));
    } else {
        const int t = threadIdx.x;
        const int wave = t >> 6;
        const int lane = t & 63;
        const int code = (blockIdx.x - XB) * 4 + wave;
        const float4* cp = (const float4*)(codes + (size_t)code * D_SZ);
        float s = 0.0f;
        #pragma unroll
        for (int u = 0; u < 2; ++u) {
            const float4 v = cp[lane + 64 * u];
            ((ushort4*)chi)[(size_t)code * (D_SZ / 4) + lane + 64 * u] =
                make_ushort4(f2bf(v.x), f2bf(v.y), f2bf(v.z), f2bf(v.w));
            s = fmaf(v.x, v.x, s); s = fmaf(v.y, v.y, s);
            s = fmaf(v.z, v.z, s); s = fmaf(v.w, v.w, s);
        }
        #pragma unroll
        for (int off = 32; off; off >>= 1) s += __shfl_down(s, off, 64);
        if (lane == 0) csq[code] = s;
    }
}

// ---------------------------------------------------------------------------
// Main: hi*hi bf16 MFMA GEMM, 256x256 tile, 8-phase schedule (HK-style):
// BK=64, 8 waves (2M x 4N), per-wave 128x64 output (acc[8][4] = 128 VGPR).
// LDS 128 KiB = 2 K-tile double buffer, XOR-swizzled (chunk' = chunk ^
// (row&7)) via pre-swizzled global src. Phase = {ds_read subtile | stage 1
// half-tile} -> barrier -> lgkmcnt(0) -> setprio(1) 16xMFMA setprio(0) ->
// barrier. Counted vmcnt(6) ONLY at phases 4/8; never 0 in the main loop.
//
// vmcnt ledger (2 gload16 per STG; per-wave counts; loads retire in order;
// each VMCNT(n)+BARRIER => ALL waves' corresponding loads landed):
//   prologue: d0.{B0,B1,A0,A1} + d1.{B0,B1,A0} = 14 issued;
//             VMCNT(6) retires oldest 8 = ALL of d0; BARRIER.
//   ph1: read d0.B+A q0 | stage d1.Ahi(kt+1)          -> 8 in flight
//   ph2: read d0.A q1   | stage d0.B0 (kt+2)          -> 10
//   ph3: read d0.A q2   | stage d0.B1 (kt+2)          -> 12
//   ph4: read d0.A q3   | stage d0.Alo(kt+2); VMCNT(6)-> d1(kt+1) landed
//   ph5: read d1.B+A q0 | stage d0.Ahi(kt+2)          -> 8
//   ph6: read d1.A q1   | stage d1.B0 (kt+3)          -> 10
//   ph7: read d1.A q2   | stage d1.B1 (kt+3)          -> 12
//   ph8: read d1.A q3   | stage d1.Alo(kt+3); VMCNT(6)-> d0(kt+2) landed
// Overwrite-safety: STG into region R only after the barrier that all
// readers of R's old data passed with ds_reads complete (lgkmcnt before
// their MFMA cluster precedes that barrier).
// ---------------------------------------------------------------------------
__global__ __launch_bounds__(512, 2) void gemm_argmin_kernel(
        const unsigned short* __restrict__ xhi,
        const unsigned short* __restrict__ chi,
        const float* __restrict__ csq,
        uint2* __restrict__ table) {
    __shared__ unsigned short sA[2][256][64];   // 64 KB
    __shared__ unsigned short sB[2][256][64];   // 64 KB

    const int t = threadIdx.x;
    const int wave = t >> 6;     // 0..7
    const int lane = t & 63;
    const int quad = lane >> 4;
    const int l15 = lane & 15;
    const int wm = wave >> 2;    // 0..1 -> 128-row half
    const int wn = wave & 3;     // 0..3 -> 64-col quarter

    const int rowbase = blockIdx.y * 256;   // x rows
    const int colbase = blockIdx.x * 256;   // code cols

    // staging geometry: each gload16 stages 8 rows x 128B, linear LDS dest,
    // pre-swizzled global source (chunk ^ row&7).
    const int lrow = lane >> 3;                 // 0..7
    const int lch  = (lane & 7) ^ lrow;         // swizzled 16B-chunk source
    const int arb = wm * 128 + wn * 16;         // wave's A rows (lo half)
    const int brb = wave * 16;                  // wave's B rows (B0 half)
    const unsigned short* gArow = xhi + (size_t)(rowbase + arb + lrow) * D_SZ + lch * 8;
    const unsigned short* gBrow = chi + (size_t)(colbase + brb + lrow) * D_SZ + lch * 8;

#define STG_A(d, kt, half) do { \
        const unsigned short* _g = gArow + (size_t)(half) * 64 * D_SZ + (kt) * 64; \
        gload16(_g,                    &sA[d][arb + (half) * 64][0]); \
        gload16(_g + (size_t)8 * D_SZ, &sA[d][arb + (half) * 64 + 8][0]); \
    } while (0)
#define STG_B(d, kt, half) do { \
        const unsigned short* _g = gBrow + (size_t)(half) * 128 * D_SZ + (kt) * 64; \
        gload16(_g,                    &sB[d][brb + (half) * 128][0]); \
        gload16(_g + (size_t)8 * D_SZ, &sB[d][brb + (half) * 128 + 8][0]); \
    } while (0)

    short8 af[2][2], bf[4][2];
    floatx4 acc[8][4];
    #pragma unroll
    for (int m = 0; m < 8; ++m)
        #pragma unroll
        for (int n = 0; n < 4; ++n) acc[m][n] = (floatx4)0.0f;

#define LDB(d) do { \
        _Pragma("unroll") for (int n = 0; n < 4; ++n) \
            _Pragma("unroll") for (int kk = 0; kk < 2; ++kk) \
                bf[n][kk] = *(const short8*)&sB[d][wn * 64 + n * 16 + l15] \
                                               [((kk * 4 + quad) ^ (l15 & 7)) * 8]; \
    } while (0)
#define LDA(d, p) do { \
        _Pragma("unroll") for (int i = 0; i < 2; ++i) \
            _Pragma("unroll") for (int kk = 0; kk < 2; ++kk) \
                af[i][kk] = *(const short8*)&sA[d][wm * 128 + ((p) * 2 + i) * 16 + l15] \
                                               [((kk * 4 + quad) ^ (l15 & 7)) * 8]; \
    } while (0)
#define MM(p) do { \
        __builtin_amdgcn_s_setprio(1); \
        _Pragma("unroll") for (int i = 0; i < 2; ++i) \
            _Pragma("unroll") for (int n = 0; n < 4; ++n) \
                _Pragma("unroll") for (int kk = 0; kk < 2; ++kk) \
                    acc[(p) * 2 + i][n] = __builtin_amdgcn_mfma_f32_16x16x32_bf16( \
                        af[i][kk], bf[n][kk], acc[(p) * 2 + i][n], 0, 0, 0); \
        __builtin_amdgcn_s_setprio(0); \
        SCHEDB(); \
    } while (0)
// Leading barrier + rule-#18 lgkmcnt pin; trailing barrier.
#define PHASE_SYNC_IN()  do { SCHEDB(); BARRIER(); LGKM0(); } while (0)
#define PHASE_SYNC_OUT() do { BARRIER(); } while (0)

    // ---- prologue: kt0 -> d0 complete; kt1 -> d1 minus Ahi
    STG_B(0, 0, 0); STG_B(0, 0, 1); STG_A(0, 0, 0); STG_A(0, 0, 1);
    STG_B(1, 1, 0); STG_B(1, 1, 1); STG_A(1, 1, 0);
    VMCNT(6);                        // retire oldest 8 of 14 = ALL of d0
    BARRIER();

    for (int it = 0; it < 4; ++it) {
        const int k0 = it * 2;
        const bool last = (it == 3);
        // ph1
        LDB(0); LDA(0, 0);
        STG_A(1, k0 + 1, 1);
        PHASE_SYNC_IN(); MM(0); PHASE_SYNC_OUT();
        // ph2
        LDA(0, 1);
        if (!last) STG_B(0, k0 + 2, 0);
        PHASE_SYNC_IN(); MM(1); PHASE_SYNC_OUT();
        // ph3
        LDA(0, 2);
        if (!last) STG_B(0, k0 + 2, 1);
        PHASE_SYNC_IN(); MM(2); PHASE_SYNC_OUT();
        // ph4
        LDA(0, 3);
        if (!last) { STG_A(0, k0 + 2, 0); VMCNT(6); } else { VMCNT(0); }
        PHASE_SYNC_IN(); MM(3); PHASE_SYNC_OUT();
        // ph5
        LDB(1); LDA(1, 0);
        if (!last) STG_A(0, k0 + 2, 1);
        PHASE_SYNC_IN(); MM(0); PHASE_SYNC_OUT();
        // ph6
        LDA(1, 1);
        if (!last) STG_B(1, k0 + 3, 0);
        PHASE_SYNC_IN(); MM(1); PHASE_SYNC_OUT();
        // ph7
        LDA(1, 2);
        if (!last) STG_B(1, k0 + 3, 1);
        PHASE_SYNC_IN(); MM(2); PHASE_SYNC_OUT();
        // ph8
        LDA(1, 3);
        if (!last) { STG_A(1, k0 + 3, 0); VMCNT(6); }
        PHASE_SYNC_IN(); MM(3); PHASE_SYNC_OUT();
    }

    // ---- epilogue: packed-key top-2 per (row, this wave's 64-col half).
    const int hb = blockIdx.x * 4 + wn;   // 64-col half index, 0..63
    float cs2[4];
    #pragma unroll
    for (int n = 0; n < 4; ++n)
        cs2[n] = fmaf(0.5f, csq[colbase + wn * 64 + n * 16 + l15], DBIAS);

    #pragma unroll
    for (int m = 0; m < 8; ++m) {
        #pragma unroll
        for (int r = 0; r < 4; ++r) {
            unsigned k[4];
            #pragma unroll
            for (int n = 0; n < 4; ++n) {
                const float dd = cs2[n] - acc[m][n][r];   // > 0 by DBIAS
                k[n] = (__float_as_uint(dd) & 0xFFFFFFC0u) | (unsigned)(n * 16 + l15);
            }
            // top-2-of-4 min/max network
            const unsigned lo1 = min(k[0], k[1]), hi1 = max(k[0], k[1]);
            const unsigned lo2 = min(k[2], k[3]), hi2 = max(k[2], k[3]);
            unsigned k1 = min(lo1, lo2);
            unsigned k2 = min(max(lo1, lo2), min(hi1, hi2));
            // 16-lane top-2 merge
            #pragma unroll
            for (int off = 8; off; off >>= 1) {
                const unsigned ok1 = (unsigned)__shfl_down((int)k1, off, 16);
                const unsigned ok2 = (unsigned)__shfl_down((int)k2, off, 16);
                const unsigned hi = max(k1, ok1);
                const unsigned w2 = (k1 < ok1) ? k2 : ok2;
                k1 = min(k1, ok1);
                k2 = min(hi, w2);
            }
            if (l15 == 0) {
                const int grow = rowbase + wm * 128 + m * 16 + quad * 4 + r;
                table[(size_t)grow * 64 + hb] = make_uint2(k1, k2);
            }
        }
    }
#undef STG_A
#undef STG_B
#undef LDB
#undef LDA
#undef MM
#undef PHASE_SYNC_IN
#undef PHASE_SYNC_OUT
}

// ---------------------------------------------------------------------------
// Re-rank + gather + loss. FOUR rows per wave (4x memory-level parallelism:
// batch 4 table loads + 8 x loads, resolve 4 fins, then 8 independent gather
// loads). Keys are positive-float bits; col = 64*lane + (key & 63).
// ---------------------------------------------------------------------------
__global__ __launch_bounds__(256) void rerank_gather_loss_kernel(
        const float* __restrict__ x,
        const float* __restrict__ codes,
        const float* __restrict__ csq,
        const uint2* __restrict__ table,
        float* __restrict__ outq,
        float* __restrict__ out_idx_f,
        float* __restrict__ partials) {
    __shared__ float red[4];
    const int t = threadIdx.x;
    const int wave = t >> 6;
    const int lane = t & 63;
    const int row0 = (blockIdx.x * 4 + wave) * 4;   // 4 consecutive rows

    // ---- batched independent loads: 4 table entries + 4 x rows
    uint2 e[4];
    float4 xv[4][2];
    #pragma unroll
    for (int r = 0; r < 4; ++r) {
        e[r] = table[(size_t)(row0 + r) * 64 + lane];
        const float4* xp = (const float4*)(x + (size_t)(row0 + r) * D_SZ);
        xv[r][0] = xp[lane];
        xv[r][1] = xp[lane + 64];
    }

    // ---- resolve argmin per row
    int fin[4];
    #pragma unroll
    for (int r = 0; r < 4; ++r) {
        const unsigned k1 = e[r].x, k2 = e[r].y;
        unsigned mk = k1;
        #pragma unroll
        for (int off = 32; off; off >>= 1)
            mk = min(mk, (unsigned)__shfl_xor((int)mk, off, 64));

        const float thr = __uint_as_float(mk & 0xFFFFFFC0u) + EPS;
        const float v1 = __uint_as_float(k1 & 0xFFFFFFC0u);
        const float v2 = __uint_as_float(k2 & 0xFFFFFFC0u);
        const unsigned long long b1 = __ballot(v1 <= thr);
        const unsigned long long b2 = __ballot(v2 <= thr);

        const unsigned long long bm = __ballot(k1 == mk);
        fin[r] = (__ffsll(bm) - 1) * 64 + (int)(mk & 63u);

        if (__popcll(b1) + __popcll(b2) > 1) {       // rare exact fp32 re-rank
            const int c1 = lane * 64 + (int)(k1 & 63u);
            const int c2 = lane * 64 + (int)(k2 & 63u);
            float bv = 3.4e38f; int bi = 0x7FFFFFFF;
            #pragma unroll
            for (int pass = 0; pass < 2; ++pass) {
                unsigned long long bb = pass ? b2 : b1;
                const int myc = pass ? c2 : c1;
                while (bb) {
                    const int src = __ffsll((unsigned long long)bb) - 1;
                    bb &= bb - 1;
                    const int ci = __shfl(myc, src, 64);
                    const float4* cp = (const float4*)(codes + (size_t)ci * D_SZ);
                    const float4 c0 = cp[lane];
                    const float4 c1v = cp[lane + 64];
                    float s = 0.0f;
                    s = fmaf(xv[r][0].x, c0.x, s);  s = fmaf(xv[r][0].y, c0.y, s);
                    s = fmaf(xv[r][0].z, c0.z, s);  s = fmaf(xv[r][0].w, c0.w, s);
                    s = fmaf(xv[r][1].x, c1v.x, s); s = fmaf(xv[r][1].y, c1v.y, s);
                    s = fmaf(xv[r][1].z, c1v.z, s); s = fmaf(xv[r][1].w, c1v.w, s);
                    #pragma unroll
                    for (int off = 32; off; off >>= 1) s += __shfl_xor(s, off, 64);
                    const float d = fmaf(0.5f, csq[ci], -s);   // exact fp32
                    if (d < bv || (d == bv && ci < bi)) { bv = d; bi = ci; }
                }
            }
            fin[r] = bi;
        }
    }

    // ---- batched independent gathers
    float4 qv[4][2];
    #pragma unroll
    for (int r = 0; r < 4; ++r) {
        const float4* qp = (const float4*)(codes + (size_t)fin[r] * D_SZ);
        qv[r][0] = qp[lane];
        qv[r][1] = qp[lane + 64];
    }

    // ---- writes + loss partial
    float s = 0.0f;
    #pragma unroll
    for (int r = 0; r < 4; ++r) {
        float4* op = (float4*)(outq + (size_t)(row0 + r) * D_SZ);
        op[lane] = qv[r][0];
        op[lane + 64] = qv[r][1];
        const float d0 = xv[r][0].x - qv[r][0].x, d1 = xv[r][0].y - qv[r][0].y;
        const float d2 = xv[r][0].z - qv[r][0].z, d3 = xv[r][0].w - qv[r][0].w;
        const float d4 = xv[r][1].x - qv[r][1].x, d5 = xv[r][1].y - qv[r][1].y;
        const float d6 = xv[r][1].z - qv[r][1].z, d7 = xv[r][1].w - qv[r][1].w;
        s += d0 * d0 + d1 * d1 + d2 * d2 + d3 * d3 + d4 * d4 + d5 * d5 + d6 * d6 + d7 * d7;
        if (lane == 0) out_idx_f[row0 + r] = (float)fin[r];
    }
    #pragma unroll
    for (int off = 32; off; off >>= 1) s += __shfl_down(s, off, 64);
    if (lane == 0) red[wave] = s;
    __syncthreads();
    if (t == 0) partials[blockIdx.x] = red[0] + red[1] + red[2] + red[3];
}

// ---------------------------------------------------------------------------
// Loss: sum 1024 block partials -> loss_slot. One block.
// ---------------------------------------------------------------------------
__global__ __launch_bounds__(256) void loss_reduce_kernel(const float* __restrict__ partials,
                                                          float* __restrict__ loss_slot) {
    __shared__ float red[4];
    const int t = threadIdx.x;
    const int wave = t >> 6;
    const int lane = t & 63;
    float s = 0.0f;
    #pragma unroll
    for (int i = 0; i < (B_SZ / 16) / 256; ++i) s += partials[i * 256 + t];
    #pragma unroll
    for (int off = 32; off; off >>= 1) s += __shfl_down(s, off, 64);
    if (lane == 0) red[wave] = s;
    __syncthreads();
    if (t == 0)
        *loss_slot = (red[0] + red[1] + red[2] + red[3]) * (1.25f / (float)B_SZ);
}

// ---------------------------------------------------------------------------
extern "C" void kernel_launch(void* const* d_in, const int* in_sizes, int n_in,
                              void* d_out, int out_size, void* d_ws, size_t ws_size,
                              hipStream_t stream) {
    const float* x = (const float*)d_in[0];
    const float* codes = (const float*)d_in[1];  // (1, C, D) contiguous

    float* outq = (float*)d_out;                       // [B*D]
    float* out_idx_f = outq + (size_t)B_SZ * D_SZ;     // [B]
    float* loss_slot = out_idx_f + B_SZ;               // [1]

    // workspace: xhi 16M | chi 4M | csq 16K | table 8M (uint2) | partials 4K
    unsigned short* xhi = (unsigned short*)d_ws;
    unsigned short* chi = xhi + (size_t)B_SZ * D_SZ;
    float* csq = (float*)(chi + (size_t)C_SZ * D_SZ);
    uint2* table = (uint2*)(csq + C_SZ);
    float* partials = (float*)(table + (size_t)B_SZ * 64);

    const int XB = (B_SZ * D_SZ) / 4 / 256;           // 8192
    const int CB = C_SZ / 4;                          // 1024
    convert_kernel<<<XB + CB, 256, 0, stream>>>(x, codes, xhi, chi, csq);
    gemm_argmin_kernel<<<dim3(C_SZ / 256, B_SZ / 256), 512, 0, stream>>>(xhi, chi, csq, table);
    rerank_gather_loss_kernel<<<B_SZ / 16, 256, 0, stream>>>(x, codes, csq, table, outq, out_idx_f, partials);
    loss_reduce_kernel<<<1, 256, 0, stream>>>(partials, loss_slot);
}

// Round 4
// 164.812 us; speedup vs baseline: 1.2278x; 1.2278x over previous
//
#include <hip/hip_runtime.h>

// Problem constants.
#define B_SZ 16384
#define C_SZ 4096
#define D_SZ 512

// int8 quantization scale: x, codes ~ N(0,1); ±127/22.7 = ±5.59 covers the
// max of 8.4M normal samples (max |x| ~ 5.3); clamp catches the ~1e-8 tail.
#define QSCALE 22.7f
#define INV_S2 (1.0f / (QSCALE * QSCALE))
// Re-rank threshold in "dist units" (raw_l2/2). i8 quant err per element
// std = (1/22.7)/sqrt(12) = 0.0127 -> dot err std = sqrt(512*2)*0.0127 =
// 0.41; pairwise-difference std 0.57; EPS=6 is >10 sigma of capture failure
// over all 6.7e7 (row,code) pairs. Expected candidates/row ~ exp(6*0.132)
// ~ 2.2 -> exact-fp32 re-rank stays cheap.
#define EPS 6.0f
// Bias making dist' = BIAS + 0.5*csq - dot strictly positive (needs
// BIAS > 0.5*xsq; 0.5*csq ~ 256+-45, |dot| <~ 110).
#define DBIAS 1024.0f

typedef __attribute__((ext_vector_type(4))) int intx4;      // i8 MFMA A/B/acc

// ---- helpers ---------------------------------------------------------------
__device__ inline unsigned q4(const float4 v) {
    int a = (int)rintf(v.x * QSCALE); a = max(-127, min(127, a));
    int b = (int)rintf(v.y * QSCALE); b = max(-127, min(127, b));
    int c = (int)rintf(v.z * QSCALE); c = max(-127, min(127, c));
    int d = (int)rintf(v.w * QSCALE); d = max(-127, min(127, d));
    return ((unsigned)(a & 255)) | ((unsigned)(b & 255) << 8) |
           ((unsigned)(c & 255) << 16) | ((unsigned)(d & 255) << 24);
}
__device__ inline void gload16(const void* g, void* l) {
    // async global->LDS, 16B/lane; LDS dest = wave-uniform base + lane*16
    __builtin_amdgcn_global_load_lds(
        (const __attribute__((address_space(1))) void*)g,
        (__attribute__((address_space(3))) void*)l, 16, 0, 0);
}

// ---------------------------------------------------------------------------
// Prep (fused): x -> i8 plane; codes -> i8 plane + c_sq (exact fp32).
// Blocks [0, 8192): x elements. Blocks [8192, 9216): one wave per code row.
// ---------------------------------------------------------------------------
__global__ __launch_bounds__(256) void convert_kernel(const float* __restrict__ x,
                                                      const float* __restrict__ codes,
                                                      unsigned* __restrict__ xq,
                                                      unsigned* __restrict__ cq,
                                                      float* __restrict__ csq) {
    const int XB = (B_SZ * D_SZ) / 4 / 256;   // 8192
    if (blockIdx.x < XB) {
        const int tid = blockIdx.x * 256 + threadIdx.x;
        const float4 v = ((const float4*)x)[tid];
        xq[tid] = q4(v);
    } else {
        const int t = threadIdx.x;
        const int wave = t >> 6;
        const int lane = t & 63;
        const int code = (blockIdx.x - XB) * 4 + wave;
        const float4* cp = (const float4*)(codes + (size_t)code * D_SZ);
        float s = 0.0f;
        #pragma unroll
        for (int u = 0; u < 2; ++u) {
            const float4 v = cp[lane + 64 * u];
            cq[(size_t)code * (D_SZ / 4) + lane + 64 * u] = q4(v);
            s = fmaf(v.x, v.x, s); s = fmaf(v.y, v.y, s);
            s = fmaf(v.z, v.z, s); s = fmaf(v.w, v.w, s);
        }
        #pragma unroll
        for (int off = 32; off; off >>= 1) s += __shfl_down(s, off, 64);
        if (lane == 0) csq[code] = s;
    }
}

// ---------------------------------------------------------------------------
// Main: i8 MFMA GEMM (mfma_i32_16x16x64_i8, 2x K per instr vs bf16),
// 128x128 block tile, 8 waves (512 thr), wave = 32 rows x 64 cols,
// acc[2][4]. EXACT R0 skeleton (proven 103us at bf16): BK-tile rows are
// 128 B (now 128 i8 instead of 64 bf16), so the XOR swizzle (16B chunk' =
// chunk ^ (row&7)), gload16 staging, and fragment addressing carry over
// byte-identically. K-loop: D/128 = 4 tiles, 2 k64-subs each -> 16 MFMA
// per wave per tile (64 total vs 128 bf16). 2 syncthreads per tile.
// Epilogue: dist' = (DBIAS + 0.5*csq) - iacc*INV_S2 > 0 -> float bits are
// order-monotone; key = (bits & ~63) | col-low-6. Top-2 of 4, 16-lane
// merge, one uint2 store per (row, 64-col half). NO atomics, NO fences.
// ---------------------------------------------------------------------------
__global__ __launch_bounds__(512, 6) void gemm_argmin_kernel(
        const unsigned char* __restrict__ xq,
        const unsigned char* __restrict__ cq,
        const float* __restrict__ csq,
        uint2* __restrict__ table) {
    __shared__ unsigned char sA[128][128];   // 16 KB
    __shared__ unsigned char sB[128][128];   // 16 KB

    const int t = threadIdx.x;
    const int wave = t >> 6;     // 0..7
    const int lane = t & 63;
    const int quad = lane >> 4;
    const int l15 = lane & 15;

    const int rowbase = blockIdx.y * 128;   // x rows
    const int colbase = blockIdx.x * 128;   // code cols
    const int wr = (wave >> 1) * 32;        // wave's 32-row strip
    const int wc = (wave & 1) * 64;         // wave's 64-col half

    // staging: waves 0-3 stage A rows w*32..+32; waves 4-7 stage B similarly.
    const unsigned char* gsrc;
    unsigned char(*ltile)[128];
    int rowoff;
    if (wave < 4) { gsrc = xq ? xq + (size_t)rowbase * D_SZ : xq; ltile = sA; rowoff = wave * 32; }
    else          { gsrc = cq + (size_t)colbase * D_SZ; ltile = sB; rowoff = (wave - 4) * 32; }
    const int lrow = lane >> 3;                       // 0..7 within 8-row group
    const int lchunk = (lane & 7) ^ (lrow & 7);       // swizzled 16B-chunk source
    const unsigned char* gbase = gsrc + (size_t)(rowoff + lrow) * D_SZ + lchunk * 16;

    // epilogue csq terms, loaded up front (L2-resident)
    float cs2[4];
    #pragma unroll
    for (int j = 0; j < 4; ++j)
        cs2[j] = fmaf(0.5f, csq[colbase + wc + j * 16 + l15], DBIAS);

    intx4 acc[2][4];
    #pragma unroll
    for (int i = 0; i < 2; ++i)
        #pragma unroll
        for (int j = 0; j < 4; ++j) acc[i][j] = (intx4)0;

    for (int kt = 0; kt < D_SZ / 128; ++kt) {
        const unsigned char* g = gbase + kt * 128;
        #pragma unroll
        for (int inst = 0; inst < 4; ++inst)
            gload16(g + (size_t)(inst * 8) * D_SZ, &ltile[rowoff + inst * 8][0]);
        __syncthreads();

        #pragma unroll
        for (int ksub = 0; ksub < 2; ++ksub) {
            const int cc = (((ksub * 4 + quad) ^ (l15 & 7))) * 16;   // byte offset
            intx4 a[2], b[4];
            #pragma unroll
            for (int i = 0; i < 2; ++i)
                a[i] = *(const intx4*)&sA[wr + i * 16 + l15][cc];
            #pragma unroll
            for (int j = 0; j < 4; ++j)
                b[j] = *(const intx4*)&sB[wc + j * 16 + l15][cc];
            #pragma unroll
            for (int i = 0; i < 2; ++i)
                #pragma unroll
                for (int j = 0; j < 4; ++j)
                    acc[i][j] = __builtin_amdgcn_mfma_i32_16x16x64_i8(a[i], b[j], acc[i][j], 0, 0, 0);
        }
        __syncthreads();
    }

    // ---- epilogue: packed-key top-2 per (row, this wave's 64-col half)
    const int hb = blockIdx.x * 2 + (wave & 1);   // 64-col half index, 0..63

    #pragma unroll
    for (int i = 0; i < 2; ++i) {
        #pragma unroll
        for (int r = 0; r < 4; ++r) {
            unsigned k[4];
            #pragma unroll
            for (int j = 0; j < 4; ++j) {
                const float d = fmaf(-(float)acc[i][j][r], INV_S2, cs2[j]);   // > 0 by DBIAS
                k[j] = (__float_as_uint(d) & 0xFFFFFFC0u) | (unsigned)(j * 16 + l15);
            }
            // top-2-of-4 min/max network
            const unsigned lo1 = min(k[0], k[1]), hi1 = max(k[0], k[1]);
            const unsigned lo2 = min(k[2], k[3]), hi2 = max(k[2], k[3]);
            unsigned k1 = min(lo1, lo2);
            unsigned k2 = min(max(lo1, lo2), min(hi1, hi2));
            // 16-lane top-2 merge
            #pragma unroll
            for (int off = 8; off; off >>= 1) {
                const unsigned ok1 = (unsigned)__shfl_down((int)k1, off, 16);
                const unsigned ok2 = (unsigned)__shfl_down((int)k2, off, 16);
                const unsigned hi = max(k1, ok1);
                const unsigned w2 = (k1 < ok1) ? k2 : ok2;
                k1 = min(k1, ok1);
                k2 = min(hi, w2);
            }
            if (l15 == 0) {
                const int grow = rowbase + wr + i * 16 + quad * 4 + r;
                table[(size_t)grow * 64 + hb] = make_uint2(k1, k2);
            }
        }
    }
}

// ---------------------------------------------------------------------------
// Re-rank + gather + loss. FOUR rows per wave (4x memory-level parallelism:
// batch 4 table loads + 8 x loads, resolve 4 fins, then 8 independent gather
// loads). Keys are positive-float bits; col = 64*lane + (key & 63).
// Exact fp32 re-rank of all candidates within EPS -> indices bit-exact.
// ---------------------------------------------------------------------------
__global__ __launch_bounds__(256) void rerank_gather_loss_kernel(
        const float* __restrict__ x,
        const float* __restrict__ codes,
        const float* __restrict__ csq,
        const uint2* __restrict__ table,
        float* __restrict__ outq,
        float* __restrict__ out_idx_f,
        float* __restrict__ partials) {
    __shared__ float red[4];
    const int t = threadIdx.x;
    const int wave = t >> 6;
    const int lane = t & 63;
    const int row0 = (blockIdx.x * 4 + wave) * 4;   // 4 consecutive rows

    // ---- batched independent loads: 4 table entries + 4 x rows
    uint2 e[4];
    float4 xv[4][2];
    #pragma unroll
    for (int r = 0; r < 4; ++r) {
        e[r] = table[(size_t)(row0 + r) * 64 + lane];
        const float4* xp = (const float4*)(x + (size_t)(row0 + r) * D_SZ);
        xv[r][0] = xp[lane];
        xv[r][1] = xp[lane + 64];
    }

    // ---- resolve argmin per row
    int fin[4];
    #pragma unroll
    for (int r = 0; r < 4; ++r) {
        const unsigned k1 = e[r].x, k2 = e[r].y;
        unsigned mk = k1;
        #pragma unroll
        for (int off = 32; off; off >>= 1)
            mk = min(mk, (unsigned)__shfl_xor((int)mk, off, 64));

        const float thr = __uint_as_float(mk & 0xFFFFFFC0u) + EPS;
        const float v1 = __uint_as_float(k1 & 0xFFFFFFC0u);
        const float v2 = __uint_as_float(k2 & 0xFFFFFFC0u);
        const unsigned long long b1 = __ballot(v1 <= thr);
        const unsigned long long b2 = __ballot(v2 <= thr);

        const unsigned long long bm = __ballot(k1 == mk);
        fin[r] = (__ffsll(bm) - 1) * 64 + (int)(mk & 63u);

        if (__popcll(b1) + __popcll(b2) > 1) {       // exact fp32 re-rank
            const int c1 = lane * 64 + (int)(k1 & 63u);
            const int c2 = lane * 64 + (int)(k2 & 63u);
            float bv = 3.4e38f; int bi = 0x7FFFFFFF;
            #pragma unroll
            for (int pass = 0; pass < 2; ++pass) {
                unsigned long long bb = pass ? b2 : b1;
                const int myc = pass ? c2 : c1;
                while (bb) {
                    const int src = __ffsll((unsigned long long)bb) - 1;
                    bb &= bb - 1;
                    const int ci = __shfl(myc, src, 64);
                    const float4* cp = (const float4*)(codes + (size_t)ci * D_SZ);
                    const float4 c0 = cp[lane];
                    const float4 c1v = cp[lane + 64];
                    float s = 0.0f;
                    s = fmaf(xv[r][0].x, c0.x, s);  s = fmaf(xv[r][0].y, c0.y, s);
                    s = fmaf(xv[r][0].z, c0.z, s);  s = fmaf(xv[r][0].w, c0.w, s);
                    s = fmaf(xv[r][1].x, c1v.x, s); s = fmaf(xv[r][1].y, c1v.y, s);
                    s = fmaf(xv[r][1].z, c1v.z, s); s = fmaf(xv[r][1].w, c1v.w, s);
                    #pragma unroll
                    for (int off = 32; off; off >>= 1) s += __shfl_xor(s, off, 64);
                    const float d = fmaf(0.5f, csq[ci], -s);   // exact fp32
                    if (d < bv || (d == bv && ci < bi)) { bv = d; bi = ci; }
                }
            }
            fin[r] = bi;
        }
    }

    // ---- batched independent gathers
    float4 qv[4][2];
    #pragma unroll
    for (int r = 0; r < 4; ++r) {
        const float4* qp = (const float4*)(codes + (size_t)fin[r] * D_SZ);
        qv[r][0] = qp[lane];
        qv[r][1] = qp[lane + 64];
    }

    // ---- writes + loss partial
    float s = 0.0f;
    #pragma unroll
    for (int r = 0; r < 4; ++r) {
        float4* op = (float4*)(outq + (size_t)(row0 + r) * D_SZ);
        op[lane] = qv[r][0];
        op[lane + 64] = qv[r][1];
        const float d0 = xv[r][0].x - qv[r][0].x, d1 = xv[r][0].y - qv[r][0].y;
        const float d2 = xv[r][0].z - qv[r][0].z, d3 = xv[r][0].w - qv[r][0].w;
        const float d4 = xv[r][1].x - qv[r][1].x, d5 = xv[r][1].y - qv[r][1].y;
        const float d6 = xv[r][1].z - qv[r][1].z, d7 = xv[r][1].w - qv[r][1].w;
        s += d0 * d0 + d1 * d1 + d2 * d2 + d3 * d3 + d4 * d4 + d5 * d5 + d6 * d6 + d7 * d7;
        if (lane == 0) out_idx_f[row0 + r] = (float)fin[r];
    }
    #pragma unroll
    for (int off = 32; off; off >>= 1) s += __shfl_down(s, off, 64);
    if (lane == 0) red[wave] = s;
    __syncthreads();
    if (t == 0) partials[blockIdx.x] = red[0] + red[1] + red[2] + red[3];
}

// ---------------------------------------------------------------------------
// Loss: sum 1024 block partials -> loss_slot. One block.
// ---------------------------------------------------------------------------
__global__ __launch_bounds__(256) void loss_reduce_kernel(const float* __restrict__ partials,
                                                          float* __restrict__ loss_slot) {
    __shared__ float red[4];
    const int t = threadIdx.x;
    const int wave = t >> 6;
    const int lane = t & 63;
    float s = 0.0f;
    #pragma unroll
    for (int i = 0; i < (B_SZ / 16) / 256; ++i) s += partials[i * 256 + t];
    #pragma unroll
    for (int off = 32; off; off >>= 1) s += __shfl_down(s, off, 64);
    if (lane == 0) red[wave] = s;
    __syncthreads();
    if (t == 0)
        *loss_slot = (red[0] + red[1] + red[2] + red[3]) * (1.25f / (float)B_SZ);
}

// ---------------------------------------------------------------------------
extern "C" void kernel_launch(void* const* d_in, const int* in_sizes, int n_in,
                              void* d_out, int out_size, void* d_ws, size_t ws_size,
                              hipStream_t stream) {
    const float* x = (const float*)d_in[0];
    const float* codes = (const float*)d_in[1];  // (1, C, D) contiguous

    float* outq = (float*)d_out;                       // [B*D]
    float* out_idx_f = outq + (size_t)B_SZ * D_SZ;     // [B]
    float* loss_slot = out_idx_f + B_SZ;               // [1]

    // workspace: xq 8M | cq 2M | csq 16K | table 8M (uint2) | partials 4K
    unsigned char* xq = (unsigned char*)d_ws;
    unsigned char* cq = xq + (size_t)B_SZ * D_SZ;
    float* csq = (float*)(cq + (size_t)C_SZ * D_SZ);
    uint2* table = (uint2*)(csq + C_SZ);
    float* partials = (float*)(table + (size_t)B_SZ * 64);

    const int XB = (B_SZ * D_SZ) / 4 / 256;           // 8192
    const int CB = C_SZ / 4;                          // 1024
    convert_kernel<<<XB + CB, 256, 0, stream>>>(x, codes, (unsigned*)xq, (unsigned*)cq, csq);
    gemm_argmin_kernel<<<dim3(C_SZ / 128, B_SZ / 128), 512, 0, stream>>>(xq, cq, csq, table);
    rerank_gather_loss_kernel<<<B_SZ / 16, 256, 0, stream>>>(x, codes, csq, table, outq, out_idx_f, partials);
    loss_reduce_kernel<<<1, 256, 0, stream>>>(partials, loss_slot);
}